// Round 2
// baseline (6156.307 us; speedup 1.0000x reference)
//
#include <hip/hip_runtime.h>
#include <hip/hip_fp16.h>

#define T_STEPS 256
#define B_SZ 8
#define HID 256

// ---- workspace layout (float offsets) ----
#define OFF_XW   0                 // (T,B,256) fused input projection  524288
#define OFF_HH   524288            // (T,B,256) hidden history          524288
#define OFF_W1T  1048576           // w1T[k][oc]   27*32
#define OFF_W2T  1049600           // w2T[k][oc]  288*64
#define OFF_W3T  1068032           // w3T[k][oc]  576*128
#define OFF_WFT  1141760           // WfuseT[m][j] 128*256 (= Wi @ enc_w, transposed)
#define OFF_BF   1174528           // bfuse[j] 256 (= ltc_b + Wi @ enc_b)
#define OFF_D1T  1174784           // dec_w1T[k][i] 256*128
#define OFF_D2T  1207552           // dec_w2T[k][i] 128*64
#define OFF_D3T  1215744           // dec_w3T[k][o]  64*6

// ---------------- prep: weight transposes + encoder/Wi fusion ----------------
__global__ __launch_bounds__(256) void prep_kernel(
    const float* __restrict__ conv1_w, const float* __restrict__ conv2_w,
    const float* __restrict__ conv3_w, const float* __restrict__ enc_w,
    const float* __restrict__ enc_b,  const float* __restrict__ ltc_wi,
    const float* __restrict__ ltc_b,  const float* __restrict__ dec_w1,
    const float* __restrict__ dec_w2, const float* __restrict__ dec_w3,
    float* __restrict__ ws)
{
  int gtid = blockIdx.x * 256 + threadIdx.x;
  int nth = gridDim.x * 256;
  // WfuseT[m*256+j] = sum_k ltc_wi[j,k] * enc_w[k,m]
  for (int e = gtid; e < 128 * 256; e += nth) {
    int j = e >> 7, m = e & 127;
    float s = 0.f;
    for (int k = 0; k < 256; ++k) s = fmaf(ltc_wi[j*256 + k], enc_w[k*128 + m], s);
    ws[OFF_WFT + m*256 + j] = s;
  }
  for (int e = gtid; e < 256; e += nth) {
    float s = ltc_b[e];
    for (int k = 0; k < 256; ++k) s = fmaf(ltc_wi[e*256 + k], enc_b[k], s);
    ws[OFF_BF + e] = s;
  }
  for (int e = gtid; e < 27*32;  e += nth) { int k = e>>5, oc = e&31;  ws[OFF_W1T+e] = conv1_w[oc*27 + k]; }
  for (int e = gtid; e < 288*64; e += nth) { int k = e>>6, oc = e&63;  ws[OFF_W2T+e] = conv2_w[oc*288 + k]; }
  for (int e = gtid; e < 576*128;e += nth) { int k = e>>7, oc = e&127; ws[OFF_W3T+e] = conv3_w[oc*576 + k]; }
  for (int e = gtid; e < 256*128;e += nth) { int k = e>>7, i  = e&127; ws[OFF_D1T+e] = dec_w1[i*256 + k]; }
  for (int e = gtid; e < 128*64; e += nth) { int k = e>>6, i  = e&63;  ws[OFF_D2T+e] = dec_w2[i*128 + k]; }
  for (int e = gtid; e < 64*6;   e += nth) { int k = e/6,  o  = e%6;   ws[OFF_D3T+e] = dec_w3[o*64 + k]; }
}

// ---------------- fused per-frame CNN encoder ----------------
// block = one (b,t) frame, 256 threads, ~33KB LDS -> 4 blocks/CU.
// uni buffer aliases: phase A = c1h [16][1024] halves, phase B = c2h [64][256] halves.
__global__ __launch_bounds__(256, 4) void enc_kernel(
    const float* __restrict__ frames,
    const float* __restrict__ b1, const float* __restrict__ b2,
    const float* __restrict__ b3, float* __restrict__ ws)
{
  __shared__ __half uni[16384];   // 32 KB
  __shared__ float fm[128];

  const int tid = threadIdx.x;
  const int bt  = blockIdx.x;
  const int b   = bt >> 8;       // T = 256
  const int t   = bt & 255;
  const float* fr  = frames + (size_t)bt * 12288;
  const float* w1T = ws + OFF_W1T;
  const float* w2T = ws + OFF_W2T;
  const float* w3T = ws + OFF_W3T;
  const float* wfT = ws + OFF_WFT;
  const float* bfu = ws + OFF_BF;

  float acc2[64];
  #pragma unroll
  for (int o = 0; o < 64; ++o) acc2[o] = b2[o];

  for (int hp = 0; hp < 2; ++hp) {
    const int ocb = hp * 16;
    // conv1 (stride2 pad1, 3->16 channels this pass), relu, -> LDS fp16
    for (int p = 0; p < 4; ++p) {
      int pos = p * 256 + tid;
      int y = pos >> 5, x = pos & 31;
      float acc[16];
      #pragma unroll
      for (int o = 0; o < 16; ++o) acc[o] = b1[ocb + o];
      for (int ic = 0; ic < 3; ++ic)
        for (int ky = 0; ky < 3; ++ky) {
          int iy = 2*y - 1 + ky;
          bool rok = (unsigned)iy < 64u;
          for (int kx = 0; kx < 3; ++kx) {
            int ix = 2*x - 1 + kx;
            float v = (rok && (unsigned)ix < 64u) ? fr[ic*4096 + iy*64 + ix] : 0.f;
            const float* wp = w1T + (ic*9 + ky*3 + kx) * 32 + ocb;
            #pragma unroll
            for (int o = 0; o < 16; ++o) acc[o] = fmaf(v, wp[o], acc[o]);
          }
        }
      #pragma unroll
      for (int o = 0; o < 16; ++o)
        uni[o*1024 + pos] = __float2half(fmaxf(acc[o], 0.f));
    }
    __syncthreads();
    // conv2 partial accumulation over these 16 input channels (acc in regs)
    {
      int y = tid >> 4, x = tid & 15;
      for (int icl = 0; icl < 16; ++icl)
        for (int ky = 0; ky < 3; ++ky) {
          int iy = 2*y - 1 + ky;
          bool rok = (unsigned)iy < 32u;
          for (int kx = 0; kx < 3; ++kx) {
            int ix = 2*x - 1 + kx;
            float v = (rok && (unsigned)ix < 32u) ? __half2float(uni[icl*1024 + iy*32 + ix]) : 0.f;
            const float* wp = w2T + ((hp*16 + icl)*9 + ky*3 + kx) * 64;
            #pragma unroll
            for (int o = 0; o < 64; ++o) acc2[o] = fmaf(v, wp[o], acc2[o]);
          }
        }
    }
    __syncthreads();   // all conv2 reads of this pass done before c1h overwrite / c2h write
  }
  // write conv2 output (relu, fp16) into the SAME buffer (c1h is dead now)
  #pragma unroll
  for (int o = 0; o < 64; ++o) uni[o*256 + tid] = __float2half(fmaxf(acc2[o], 0.f));
  __syncthreads();
  // conv3: thread = (pos 0..63 = lane, ocgroup 0..3 = wave)
  const int g = tid >> 6, pos = tid & 63;
  const int y3 = pos >> 3, x3 = pos & 7;
  float acc3[32];
  #pragma unroll
  for (int o = 0; o < 32; ++o) acc3[o] = b3[g*32 + o];
  for (int ic = 0; ic < 64; ++ic)
    for (int ky = 0; ky < 3; ++ky) {
      int iy = 2*y3 - 1 + ky;
      bool rok = (unsigned)iy < 16u;
      for (int kx = 0; kx < 3; ++kx) {
        int ix = 2*x3 - 1 + kx;
        float v = (rok && (unsigned)ix < 16u) ? __half2float(uni[ic*256 + iy*16 + ix]) : 0.f;
        const float* wp = w3T + (ic*9 + ky*3 + kx) * 128 + g*32;
        #pragma unroll
        for (int o = 0; o < 32; ++o) acc3[o] = fmaf(v, wp[o], acc3[o]);
      }
    }
  // spatial mean per channel: pure wave-level shuffle reduction (pos == lane)
  #pragma unroll
  for (int o = 0; o < 32; ++o) {
    float v = fmaxf(acc3[o], 0.f);
    v += __shfl_xor(v, 1);
    v += __shfl_xor(v, 2);
    v += __shfl_xor(v, 4);
    v += __shfl_xor(v, 8);
    v += __shfl_xor(v, 16);
    v += __shfl_xor(v, 32);
    if (pos == 0) fm[g*32 + o] = v * (1.f/64.f);
  }
  __syncthreads();
  {
    float accx = bfu[tid];
    for (int m = 0; m < 128; ++m) accx = fmaf(fm[m], wfT[m*256 + tid], accx);
    ws[OFF_XW + (t*B_SZ + b)*HID + tid] = accx;
  }
}

// ---------------- sequential LTC scan: 1 block per batch ----------------
__global__ __launch_bounds__(1024) void scan_kernel(
    const float* __restrict__ wr, const float* __restrict__ tau,
    const float* __restrict__ av, const float* __restrict__ h0,
    float* __restrict__ ws, float* __restrict__ outh)
{
  const int b = blockIdx.x;
  const int tid = threadIdx.x;
  const int j = tid & 255, q = tid >> 8;
  __shared__ float h_s[256];
  __shared__ float part[4][256];
  float4 w4[16];
  const float4* wp = (const float4*)(wr + j*256 + q*64);
  #pragma unroll
  for (int i = 0; i < 16; ++i) w4[i] = wp[i];
  const float tinv = 1.f / tau[j];
  const float aj = av[j];
  if (tid < 256) h_s[tid] = h0[b*256 + tid];
  __syncthreads();
  const float* xw = ws + OFF_XW;
  float* hh = ws + OFF_HH;
  for (int t = 0; t < T_STEPS; ++t) {
    const float4* h4 = (const float4*)(h_s + q*64);
    float s0 = 0.f, s1 = 0.f, s2 = 0.f, s3 = 0.f;
    #pragma unroll
    for (int i = 0; i < 16; ++i) {
      float4 hv = h4[i];
      s0 = fmaf(w4[i].x, hv.x, s0); s1 = fmaf(w4[i].y, hv.y, s1);
      s2 = fmaf(w4[i].z, hv.z, s2); s3 = fmaf(w4[i].w, hv.w, s3);
    }
    part[q][j] = (s0 + s1) + (s2 + s3);
    __syncthreads();
    float pre = part[0][j] + part[1][j] + part[2][j] + part[3][j]
              + xw[(t*B_SZ + b)*HID + j];
    float f = 1.f - 2.f / (1.f + __expf(2.f * pre));
    float hv0 = h_s[j];
    float hn = fmaf(0.1f, fmaf(-(tinv + f), hv0, f * aj), hv0);
    __syncthreads();
    h_s[j] = hn;                       // 4 q-copies write identical value
    if (q == 0) hh[(t*B_SZ + b)*HID + j] = hn;
    __syncthreads();
  }
  if (q == 0) outh[b*HID + j] = h_s[j];
}

// ---------------- decoder MLP over all (t,b), parallel ----------------
__global__ __launch_bounds__(256) void dec_kernel(
    const float* __restrict__ db1, const float* __restrict__ db2,
    const float* __restrict__ db3, const float* __restrict__ ws,
    float* __restrict__ outc)
{
  const int bid = blockIdx.x;
  const int b = bid >> 8, t = bid & 255;
  const int tid = threadIdx.x;
  __shared__ float hloc[256];
  __shared__ float p1[2][128];
  __shared__ float y1s[128];
  __shared__ float p2[4][64];
  __shared__ float y2s[64];
  const float* hh  = ws + OFF_HH + (t*B_SZ + b)*HID;
  const float* d1T = ws + OFF_D1T;
  const float* d2T = ws + OFF_D2T;
  const float* d3T = ws + OFF_D3T;
  hloc[tid] = hh[tid];
  __syncthreads();
  {
    int i = tid & 127, hf = tid >> 7;
    float s = 0.f;
    for (int k = hf*128; k < hf*128 + 128; ++k) s = fmaf(hloc[k], d1T[k*128 + i], s);
    p1[hf][i] = s;
  }
  __syncthreads();
  if (tid < 128) y1s[tid] = fmaxf(p1[0][tid] + p1[1][tid] + db1[tid], 0.f);
  __syncthreads();
  {
    int i = tid & 63, r = tid >> 6;
    float s = 0.f;
    for (int k = r*32; k < r*32 + 32; ++k) s = fmaf(y1s[k], d2T[k*64 + i], s);
    p2[r][i] = s;
  }
  __syncthreads();
  if (tid < 64) y2s[tid] = fmaxf(p2[0][tid] + p2[1][tid] + p2[2][tid] + p2[3][tid] + db2[tid], 0.f);
  __syncthreads();
  if (tid < 6) {
    float s = db3[tid];
    for (int k = 0; k < 64; ++k) s = fmaf(y2s[k], d3T[k*6 + tid], s);
    outc[(b*T_STEPS + t)*6 + tid] = s;
  }
}

extern "C" void kernel_launch(void* const* d_in, const int* in_sizes, int n_in,
                              void* d_out, int out_size, void* d_ws, size_t ws_size,
                              hipStream_t stream)
{
  const float* frames = (const float*)d_in[0];
  const float* h0   = (const float*)d_in[1];
  const float* c1w  = (const float*)d_in[2];
  const float* c1b  = (const float*)d_in[3];
  const float* c2w  = (const float*)d_in[4];
  const float* c2b  = (const float*)d_in[5];
  const float* c3w  = (const float*)d_in[6];
  const float* c3b  = (const float*)d_in[7];
  const float* encw = (const float*)d_in[8];
  const float* encb = (const float*)d_in[9];
  const float* wr   = (const float*)d_in[10];
  const float* wi   = (const float*)d_in[11];
  const float* lb   = (const float*)d_in[12];
  const float* ltau = (const float*)d_in[13];
  const float* la   = (const float*)d_in[14];
  const float* dw1  = (const float*)d_in[15];
  const float* db1  = (const float*)d_in[16];
  const float* dw2  = (const float*)d_in[17];
  const float* db2  = (const float*)d_in[18];
  const float* dw3  = (const float*)d_in[19];
  const float* db3  = (const float*)d_in[20];
  float* out = (float*)d_out;
  float* ws  = (float*)d_ws;

  hipLaunchKernelGGL(prep_kernel, dim3(256), dim3(256), 0, stream,
                     c1w, c2w, c3w, encw, encb, wi, lb, dw1, dw2, dw3, ws);
  hipLaunchKernelGGL(enc_kernel, dim3(2048), dim3(256), 0, stream,
                     frames, c1b, c2b, c3b, ws);
  hipLaunchKernelGGL(scan_kernel, dim3(B_SZ), dim3(1024), 0, stream,
                     wr, ltau, la, h0, ws, out + 12288);
  hipLaunchKernelGGL(dec_kernel, dim3(2048), dim3(256), 0, stream,
                     db1, db2, db3, ws, out);
}

// Round 3
// 2276.628 us; speedup vs baseline: 2.7041x; 2.7041x over previous
//
#include <hip/hip_runtime.h>
#include <hip/hip_fp16.h>

#define T_STEPS 256
#define B_SZ 8
#define HID 256

// ---- workspace layout (float offsets) ----
#define OFF_XW   0                 // (T,B,256) fused input projection  524288
#define OFF_HH   524288            // (T,B,256) hidden history          524288
#define OFF_W1T  1048576           // w1T[k][oc]   27*32
#define OFF_W2T  1049600           // w2T[k][oc]  288*64
#define OFF_W3T  1068032           // w3T[k][oc]  576*128
#define OFF_WFT  1141760           // WfuseT[m][j] 128*256 (= Wi @ enc_w, transposed)
#define OFF_BF   1174528           // bfuse[j] 256 (= ltc_b + Wi @ enc_b)
#define OFF_D1T  1174784           // dec_w1T[k][i] 256*128
#define OFF_D2T  1207552           // dec_w2T[k][i] 128*64
#define OFF_D3T  1215744           // dec_w3T[k][o]  64*6

// ---------------- prep: weight transposes + encoder/Wi fusion ----------------
__global__ __launch_bounds__(256) void prep_kernel(
    const float* __restrict__ conv1_w, const float* __restrict__ conv2_w,
    const float* __restrict__ conv3_w, const float* __restrict__ enc_w,
    const float* __restrict__ enc_b,  const float* __restrict__ ltc_wi,
    const float* __restrict__ ltc_b,  const float* __restrict__ dec_w1,
    const float* __restrict__ dec_w2, const float* __restrict__ dec_w3,
    float* __restrict__ ws)
{
  int gtid = blockIdx.x * 256 + threadIdx.x;
  int nth = gridDim.x * 256;
  // WfuseT[m*256+j] = sum_k ltc_wi[j,k] * enc_w[k,m]
  for (int e = gtid; e < 128 * 256; e += nth) {
    int j = e >> 7, m = e & 127;
    float s = 0.f;
    for (int k = 0; k < 256; ++k) s = fmaf(ltc_wi[j*256 + k], enc_w[k*128 + m], s);
    ws[OFF_WFT + m*256 + j] = s;
  }
  for (int e = gtid; e < 256; e += nth) {
    float s = ltc_b[e];
    for (int k = 0; k < 256; ++k) s = fmaf(ltc_wi[e*256 + k], enc_b[k], s);
    ws[OFF_BF + e] = s;
  }
  for (int e = gtid; e < 27*32;  e += nth) { int k = e>>5, oc = e&31;  ws[OFF_W1T+e] = conv1_w[oc*27 + k]; }
  for (int e = gtid; e < 288*64; e += nth) { int k = e>>6, oc = e&63;  ws[OFF_W2T+e] = conv2_w[oc*288 + k]; }
  for (int e = gtid; e < 576*128;e += nth) { int k = e>>7, oc = e&127; ws[OFF_W3T+e] = conv3_w[oc*576 + k]; }
  for (int e = gtid; e < 256*128;e += nth) { int k = e>>7, i  = e&127; ws[OFF_D1T+e] = dec_w1[i*256 + k]; }
  for (int e = gtid; e < 128*64; e += nth) { int k = e>>6, i  = e&63;  ws[OFF_D2T+e] = dec_w2[i*128 + k]; }
  for (int e = gtid; e < 64*6;   e += nth) { int k = e/6,  o  = e%6;   ws[OFF_D3T+e] = dec_w3[o*64 + k]; }
}

// ---------------- fused per-frame CNN encoder ----------------
// block = one (b,t) frame, 256 threads, ~33KB LDS.
// __launch_bounds__(256,2): VGPR cap 256 -> compiler lands ~128, no spill;
// actual occupancy then 4 blocks/CU (LDS 33KB and 128 VGPR both allow 4).
__global__ __launch_bounds__(256, 2) void enc_kernel(
    const float* __restrict__ frames,
    const float* __restrict__ b1, const float* __restrict__ b2,
    const float* __restrict__ b3, float* __restrict__ ws)
{
  __shared__ __half uni[16384];   // 32 KB
  __shared__ float fm[128];

  const int tid = threadIdx.x;
  const int bt  = blockIdx.x;
  const int b   = bt >> 8;       // T = 256
  const int t   = bt & 255;
  const float* fr  = frames + (size_t)bt * 12288;
  const float* w1T = ws + OFF_W1T;
  const float* w2T = ws + OFF_W2T;
  const float* w3T = ws + OFF_W3T;
  const float* wfT = ws + OFF_WFT;
  const float* bfu = ws + OFF_BF;

  float acc2[64];
  #pragma unroll
  for (int o = 0; o < 64; ++o) acc2[o] = b2[o];

  for (int hp = 0; hp < 2; ++hp) {
    const int ocb = hp * 16;
    // conv1 (stride2 pad1, 3->16 channels this pass), relu, -> LDS fp16
    for (int p = 0; p < 4; ++p) {
      int pos = p * 256 + tid;
      int y = pos >> 5, x = pos & 31;
      float acc[16];
      #pragma unroll
      for (int o = 0; o < 16; ++o) acc[o] = b1[ocb + o];
      for (int ic = 0; ic < 3; ++ic)
        for (int ky = 0; ky < 3; ++ky) {
          int iy = 2*y - 1 + ky;
          bool rok = (unsigned)iy < 64u;
          for (int kx = 0; kx < 3; ++kx) {
            int ix = 2*x - 1 + kx;
            float v = (rok && (unsigned)ix < 64u) ? fr[ic*4096 + iy*64 + ix] : 0.f;
            const float* wp = w1T + (ic*9 + ky*3 + kx) * 32 + ocb;
            #pragma unroll
            for (int o = 0; o < 16; ++o) acc[o] = fmaf(v, wp[o], acc[o]);
          }
        }
      #pragma unroll
      for (int o = 0; o < 16; ++o)
        uni[o*1024 + pos] = __float2half(fmaxf(acc[o], 0.f));
    }
    __syncthreads();
    // conv2 partial accumulation over these 16 input channels (acc in regs)
    {
      int y = tid >> 4, x = tid & 15;
      for (int icl = 0; icl < 16; ++icl)
        for (int ky = 0; ky < 3; ++ky) {
          int iy = 2*y - 1 + ky;
          bool rok = (unsigned)iy < 32u;
          for (int kx = 0; kx < 3; ++kx) {
            int ix = 2*x - 1 + kx;
            float v = (rok && (unsigned)ix < 32u) ? __half2float(uni[icl*1024 + iy*32 + ix]) : 0.f;
            const float* wp = w2T + ((hp*16 + icl)*9 + ky*3 + kx) * 64;
            #pragma unroll
            for (int o = 0; o < 64; ++o) acc2[o] = fmaf(v, wp[o], acc2[o]);
          }
        }
    }
    __syncthreads();   // all conv2 reads of this pass done before c1h overwrite / c2h write
  }
  // write conv2 output (relu, fp16) into the SAME buffer (c1h is dead now)
  #pragma unroll
  for (int o = 0; o < 64; ++o) uni[o*256 + tid] = __float2half(fmaxf(acc2[o], 0.f));
  __syncthreads();
  // conv3: thread = (pos 0..63 = lane, ocgroup 0..3 = wave)
  const int g = tid >> 6, pos = tid & 63;
  const int y3 = pos >> 3, x3 = pos & 7;
  float acc3[32];
  #pragma unroll
  for (int o = 0; o < 32; ++o) acc3[o] = b3[g*32 + o];
  for (int ic = 0; ic < 64; ++ic)
    for (int ky = 0; ky < 3; ++ky) {
      int iy = 2*y3 - 1 + ky;
      bool rok = (unsigned)iy < 16u;
      for (int kx = 0; kx < 3; ++kx) {
        int ix = 2*x3 - 1 + kx;
        float v = (rok && (unsigned)ix < 16u) ? __half2float(uni[ic*256 + iy*16 + ix]) : 0.f;
        const float* wp = w3T + (ic*9 + ky*3 + kx) * 128 + g*32;
        #pragma unroll
        for (int o = 0; o < 32; ++o) acc3[o] = fmaf(v, wp[o], acc3[o]);
      }
    }
  // spatial mean per channel: pure wave-level shuffle reduction (pos == lane)
  #pragma unroll
  for (int o = 0; o < 32; ++o) {
    float v = fmaxf(acc3[o], 0.f);
    v += __shfl_xor(v, 1);
    v += __shfl_xor(v, 2);
    v += __shfl_xor(v, 4);
    v += __shfl_xor(v, 8);
    v += __shfl_xor(v, 16);
    v += __shfl_xor(v, 32);
    if (pos == 0) fm[g*32 + o] = v * (1.f/64.f);
  }
  __syncthreads();
  {
    float accx = bfu[tid];
    for (int m = 0; m < 128; ++m) accx = fmaf(fm[m], wfT[m*256 + tid], accx);
    ws[OFF_XW + (t*B_SZ + b)*HID + tid] = accx;
  }
}

// ---------------- sequential LTC scan: 1 block per batch ----------------
__global__ __launch_bounds__(1024) void scan_kernel(
    const float* __restrict__ wr, const float* __restrict__ tau,
    const float* __restrict__ av, const float* __restrict__ h0,
    float* __restrict__ ws, float* __restrict__ outh)
{
  const int b = blockIdx.x;
  const int tid = threadIdx.x;
  const int j = tid & 255, q = tid >> 8;
  __shared__ float h_s[256];
  __shared__ float part[4][256];
  float4 w4[16];
  const float4* wp = (const float4*)(wr + j*256 + q*64);
  #pragma unroll
  for (int i = 0; i < 16; ++i) w4[i] = wp[i];
  const float tinv = 1.f / tau[j];
  const float aj = av[j];
  if (tid < 256) h_s[tid] = h0[b*256 + tid];
  __syncthreads();
  const float* xw = ws + OFF_XW;
  float* hh = ws + OFF_HH;
  for (int t = 0; t < T_STEPS; ++t) {
    const float4* h4 = (const float4*)(h_s + q*64);
    float s0 = 0.f, s1 = 0.f, s2 = 0.f, s3 = 0.f;
    #pragma unroll
    for (int i = 0; i < 16; ++i) {
      float4 hv = h4[i];
      s0 = fmaf(w4[i].x, hv.x, s0); s1 = fmaf(w4[i].y, hv.y, s1);
      s2 = fmaf(w4[i].z, hv.z, s2); s3 = fmaf(w4[i].w, hv.w, s3);
    }
    part[q][j] = (s0 + s1) + (s2 + s3);
    __syncthreads();
    float pre = part[0][j] + part[1][j] + part[2][j] + part[3][j]
              + xw[(t*B_SZ + b)*HID + j];
    float f = 1.f - 2.f / (1.f + __expf(2.f * pre));
    float hv0 = h_s[j];
    float hn = fmaf(0.1f, fmaf(-(tinv + f), hv0, f * aj), hv0);
    __syncthreads();
    h_s[j] = hn;                       // 4 q-copies write identical value
    if (q == 0) hh[(t*B_SZ + b)*HID + j] = hn;
    __syncthreads();
  }
  if (q == 0) outh[b*HID + j] = h_s[j];
}

// ---------------- decoder MLP over all (t,b), parallel ----------------
__global__ __launch_bounds__(256) void dec_kernel(
    const float* __restrict__ db1, const float* __restrict__ db2,
    const float* __restrict__ db3, const float* __restrict__ ws,
    float* __restrict__ outc)
{
  const int bid = blockIdx.x;
  const int b = bid >> 8, t = bid & 255;
  const int tid = threadIdx.x;
  __shared__ float hloc[256];
  __shared__ float p1[2][128];
  __shared__ float y1s[128];
  __shared__ float p2[4][64];
  __shared__ float y2s[64];
  const float* hh  = ws + OFF_HH + (t*B_SZ + b)*HID;
  const float* d1T = ws + OFF_D1T;
  const float* d2T = ws + OFF_D2T;
  const float* d3T = ws + OFF_D3T;
  hloc[tid] = hh[tid];
  __syncthreads();
  {
    int i = tid & 127, hf = tid >> 7;
    float s = 0.f;
    for (int k = hf*128; k < hf*128 + 128; ++k) s = fmaf(hloc[k], d1T[k*128 + i], s);
    p1[hf][i] = s;
  }
  __syncthreads();
  if (tid < 128) y1s[tid] = fmaxf(p1[0][tid] + p1[1][tid] + db1[tid], 0.f);
  __syncthreads();
  {
    int i = tid & 63, r = tid >> 6;
    float s = 0.f;
    for (int k = r*32; k < r*32 + 32; ++k) s = fmaf(y1s[k], d2T[k*64 + i], s);
    p2[r][i] = s;
  }
  __syncthreads();
  if (tid < 64) y2s[tid] = fmaxf(p2[0][tid] + p2[1][tid] + p2[2][tid] + p2[3][tid] + db2[tid], 0.f);
  __syncthreads();
  if (tid < 6) {
    float s = db3[tid];
    for (int k = 0; k < 64; ++k) s = fmaf(y2s[k], d3T[k*6 + tid], s);
    outc[(b*T_STEPS + t)*6 + tid] = s;
  }
}

extern "C" void kernel_launch(void* const* d_in, const int* in_sizes, int n_in,
                              void* d_out, int out_size, void* d_ws, size_t ws_size,
                              hipStream_t stream)
{
  const float* frames = (const float*)d_in[0];
  const float* h0   = (const float*)d_in[1];
  const float* c1w  = (const float*)d_in[2];
  const float* c1b  = (const float*)d_in[3];
  const float* c2w  = (const float*)d_in[4];
  const float* c2b  = (const float*)d_in[5];
  const float* c3w  = (const float*)d_in[6];
  const float* c3b  = (const float*)d_in[7];
  const float* encw = (const float*)d_in[8];
  const float* encb = (const float*)d_in[9];
  const float* wr   = (const float*)d_in[10];
  const float* wi   = (const float*)d_in[11];
  const float* lb   = (const float*)d_in[12];
  const float* ltau = (const float*)d_in[13];
  const float* la   = (const float*)d_in[14];
  const float* dw1  = (const float*)d_in[15];
  const float* db1  = (const float*)d_in[16];
  const float* dw2  = (const float*)d_in[17];
  const float* db2  = (const float*)d_in[18];
  const float* dw3  = (const float*)d_in[19];
  const float* db3  = (const float*)d_in[20];
  float* out = (float*)d_out;
  float* ws  = (float*)d_ws;

  hipLaunchKernelGGL(prep_kernel, dim3(256), dim3(256), 0, stream,
                     c1w, c2w, c3w, encw, encb, wi, lb, dw1, dw2, dw3, ws);
  hipLaunchKernelGGL(enc_kernel, dim3(2048), dim3(256), 0, stream,
                     frames, c1b, c2b, c3b, ws);
  hipLaunchKernelGGL(scan_kernel, dim3(B_SZ), dim3(1024), 0, stream,
                     wr, ltau, la, h0, ws, out + 12288);
  hipLaunchKernelGGL(dec_kernel, dim3(2048), dim3(256), 0, stream,
                     db1, db2, db3, ws, out);
}

// Round 5
// 1370.430 us; speedup vs baseline: 4.4922x; 1.6613x over previous
//
#include <hip/hip_runtime.h>

#define T_STEPS 256
#define B_SZ 8
#define HID 256

typedef _Float16 hv2 __attribute__((ext_vector_type(2)));
union H2U { hv2 h; unsigned u; };
__device__ inline hv2 u2h(unsigned u){ H2U c; c.u = u; return c.h; }
__device__ inline unsigned h2u(hv2 h){ H2U c; c.h = h; return c.u; }
__device__ inline hv2 relu2(hv2 v){
  unsigned u = h2u(v);
  unsigned s = (u & 0x80008000u) >> 15;   // sign bits -> 0/1 per 16-bit lane
  u &= ~(s * 0xFFFFu);                    // zero negative lanes
  return u2h(u);
}

// ---- workspace layout (float/uint offsets) ----
#define OFF_XW   0                 // (T,B,256) fused input projection  524288
#define OFF_HH   524288            // (T,B,256) hidden history          524288
#define OFF_WFT  1141760           // WfuseT[m][j] 128*256 (= Wi @ enc_w, transposed)
#define OFF_BF   1174528           // bfuse[j] 256 (= ltc_b + Wi @ enc_b)
#define OFF_D1T  1174784           // dec_w1T[k][i] 256*128
#define OFF_D2T  1207552           // dec_w2T[k][i] 128*64
#define OFF_D3T  1215744           // dec_w3T[k][o]  64*6
#define OFF_W1P  1216128           // packed h2 conv1 w [k=27][pair=16]   432 uints
#define OFF_W2P  1216560           // packed h2 conv2 w [k=288][pair=32]  9216
#define OFF_W3P  1225776           // packed h2 conv3 w [k=576][pair=64]  36864

__device__ inline unsigned packh2f(float lo, float hi){
  hv2 h; h.x = (_Float16)lo; h.y = (_Float16)hi; return h2u(h);
}

// ---------------- prep: packed weights + transposes + encoder/Wi fusion ----------------
__global__ __launch_bounds__(256) void prep_kernel(
    const float* __restrict__ conv1_w, const float* __restrict__ conv2_w,
    const float* __restrict__ conv3_w, const float* __restrict__ enc_w,
    const float* __restrict__ enc_b,  const float* __restrict__ ltc_wi,
    const float* __restrict__ ltc_b,  const float* __restrict__ dec_w1,
    const float* __restrict__ dec_w2, const float* __restrict__ dec_w3,
    float* __restrict__ ws)
{
  int gtid = blockIdx.x * 256 + threadIdx.x;
  int nth = gridDim.x * 256;
  unsigned* wsu = (unsigned*)ws;
  // WfuseT[m*256+j] = sum_k ltc_wi[j,k] * enc_w[k,m]
  for (int e = gtid; e < 128 * 256; e += nth) {
    int j = e >> 7, m = e & 127;
    float s = 0.f;
    for (int k = 0; k < 256; ++k) s = fmaf(ltc_wi[j*256 + k], enc_w[k*128 + m], s);
    ws[OFF_WFT + m*256 + j] = s;
  }
  for (int e = gtid; e < 256; e += nth) {
    float s = ltc_b[e];
    for (int k = 0; k < 256; ++k) s = fmaf(ltc_wi[e*256 + k], enc_b[k], s);
    ws[OFF_BF + e] = s;
  }
  for (int e = gtid; e < 27*16;  e += nth) { int k = e>>4, p = e&15;
    wsu[OFF_W1P+e] = packh2f(conv1_w[(2*p)*27 + k], conv1_w[(2*p+1)*27 + k]); }
  for (int e = gtid; e < 288*32; e += nth) { int k = e>>5, p = e&31;
    wsu[OFF_W2P+e] = packh2f(conv2_w[(2*p)*288 + k], conv2_w[(2*p+1)*288 + k]); }
  for (int e = gtid; e < 576*64; e += nth) { int k = e>>6, p = e&63;
    wsu[OFF_W3P+e] = packh2f(conv3_w[(2*p)*576 + k], conv3_w[(2*p+1)*576 + k]); }
  for (int e = gtid; e < 256*128;e += nth) { int k = e>>7, i  = e&127; ws[OFF_D1T+e] = dec_w1[i*256 + k]; }
  for (int e = gtid; e < 128*64; e += nth) { int k = e>>6, i  = e&63;  ws[OFF_D2T+e] = dec_w2[i*128 + k]; }
  for (int e = gtid; e < 64*6;   e += nth) { int k = e/6,  o  = e%6;   ws[OFF_D3T+e] = dec_w3[o*64 + k]; }
}

// ---------------- fused per-frame CNN encoder (packed fp16) ----------------
// block = one (b,t) frame, 256 threads, 33KB LDS.
// Accumulators are hv2 oc-pairs: conv1 8, conv2 32, conv3 16 -> target VGPR <= ~80.
__global__ __launch_bounds__(256, 3) void enc_kernel(
    const float* __restrict__ frames,
    const float* __restrict__ b1, const float* __restrict__ b2,
    const float* __restrict__ b3, float* __restrict__ ws)
{
  __shared__ unsigned uni[8192];   // 32 KB; phase A: conv1 out [8 pair][1024 pos];
                                   // phase B: conv2 out [32 pair][256 pos]
  __shared__ float fm[128];

  const int tid = threadIdx.x;
  const int bt  = blockIdx.x;
  const int b   = bt >> 8;       // T = 256
  const int t   = bt & 255;
  const float* fr  = frames + (size_t)bt * 12288;
  const unsigned* wsu = (const unsigned*)ws;
  const hv2* w1p = (const hv2*)(wsu + OFF_W1P);
  const hv2* w2p = (const hv2*)(wsu + OFF_W2P);
  const hv2* w3p = (const hv2*)(wsu + OFF_W3P);
  const _Float16* uniH = (const _Float16*)uni;
  const float* wfT = ws + OFF_WFT;
  const float* bfu = ws + OFF_BF;

  hv2 acc2[32];
  #pragma unroll
  for (int o = 0; o < 32; ++o) { acc2[o].x = (_Float16)b2[2*o]; acc2[o].y = (_Float16)b2[2*o+1]; }

  for (int hp = 0; hp < 2; ++hp) {
    // conv1 (stride2 pad1, 3->16 oc this pass = 8 pairs), relu -> LDS h2-interleaved
    for (int p = 0; p < 4; ++p) {
      int pos = p * 256 + tid;
      int y = pos >> 5, x = pos & 31;
      hv2 a1[8];
      #pragma unroll
      for (int o = 0; o < 8; ++o) { a1[o].x = (_Float16)b1[16*hp+2*o]; a1[o].y = (_Float16)b1[16*hp+2*o+1]; }
      for (int ic = 0; ic < 3; ++ic)
        for (int ky = 0; ky < 3; ++ky) {
          int iy = 2*y - 1 + ky;
          bool rok = (unsigned)iy < 64u;
          for (int kx = 0; kx < 3; ++kx) {
            int ix = 2*x - 1 + kx;
            float v = (rok && (unsigned)ix < 64u) ? fr[ic*4096 + iy*64 + ix] : 0.f;
            _Float16 hvv = (_Float16)v;
            hv2 vs; vs.x = hvv; vs.y = hvv;
            const hv2* wp = w1p + (ic*9 + ky*3 + kx)*16 + hp*8;
            #pragma unroll
            for (int o = 0; o < 8; ++o) a1[o] = vs * wp[o] + a1[o];
          }
        }
      #pragma unroll
      for (int o = 0; o < 8; ++o)
        uni[o*1024 + pos] = h2u(relu2(a1[o]));
    }
    __syncthreads();
    // conv2 partial accumulation over these 16 input channels (hv2 acc in regs)
    {
      int y = tid >> 4, x = tid & 15;
      for (int icl = 0; icl < 16; ++icl) {
        int qp = icl >> 1, s = icl & 1;
        const int kb = (hp*16 + icl)*9;
        for (int ky = 0; ky < 3; ++ky) {
          int iy = 2*y - 1 + ky;
          bool rok = (unsigned)iy < 32u;
          for (int kx = 0; kx < 3; ++kx) {
            int ix = 2*x - 1 + kx;
            _Float16 hvv = (rok && (unsigned)ix < 32u)
                        ? uniH[qp*2048 + 2*(iy*32 + ix) + s] : (_Float16)0.f;
            hv2 vs; vs.x = hvv; vs.y = hvv;
            const hv2* wp = w2p + (kb + ky*3 + kx)*32;
            #pragma unroll
            for (int o = 0; o < 32; ++o) acc2[o] = vs * wp[o] + acc2[o];
          }
        }
      }
    }
    __syncthreads();   // conv2 reads done before next pass overwrites / conv2-out write
  }
  // conv2 out (relu) -> LDS [32 pair][256 pos], one b32 per pair
  #pragma unroll
  for (int o = 0; o < 32; ++o)
    uni[o*256 + tid] = h2u(relu2(acc2[o]));
  __syncthreads();
  // conv3: thread = (q 0..63 = lane, ocgroup g 0..3 = wave); 16 oc-pairs per thread
  const int g = tid >> 6, q = tid & 63;
  const int y3 = q >> 3, x3 = q & 7;
  hv2 a3[16];
  #pragma unroll
  for (int o = 0; o < 16; ++o) { a3[o].x = (_Float16)b3[g*32+2*o]; a3[o].y = (_Float16)b3[g*32+2*o+1]; }
  for (int ic = 0; ic < 64; ++ic) {
    int qp = ic >> 1, s = ic & 1;
    for (int ky = 0; ky < 3; ++ky) {
      int iy = 2*y3 - 1 + ky;
      bool rok = (unsigned)iy < 16u;
      for (int kx = 0; kx < 3; ++kx) {
        int ix = 2*x3 - 1 + kx;
        _Float16 hvv = (rok && (unsigned)ix < 16u)
                    ? uniH[qp*512 + 2*(iy*16 + ix) + s] : (_Float16)0.f;
        hv2 vs; vs.x = hvv; vs.y = hvv;
        const hv2* wp = w3p + (ic*9 + ky*3 + kx)*64 + g*16;
        #pragma unroll
        for (int o = 0; o < 16; ++o) a3[o] = vs * wp[o] + a3[o];
      }
    }
  }
  // relu + spatial mean: hv2 shuffle-tree over the 64 lanes (q == lane)
  #pragma unroll
  for (int o = 0; o < 16; ++o) {
    hv2 r = relu2(a3[o]);
    r = r + u2h(__shfl_xor(h2u(r), 1));
    r = r + u2h(__shfl_xor(h2u(r), 2));
    r = r + u2h(__shfl_xor(h2u(r), 4));
    r = r + u2h(__shfl_xor(h2u(r), 8));
    r = r + u2h(__shfl_xor(h2u(r), 16));
    r = r + u2h(__shfl_xor(h2u(r), 32));
    if (q == 0) {
      fm[g*32 + 2*o]     = (float)r.x * (1.f/64.f);
      fm[g*32 + 2*o + 1] = (float)r.y * (1.f/64.f);
    }
  }
  __syncthreads();
  {
    float accx = bfu[tid];
    for (int m = 0; m < 128; ++m) accx = fmaf(fm[m], wfT[m*256 + tid], accx);
    ws[OFF_XW + (t*B_SZ + b)*HID + tid] = accx;
  }
}

// ---------------- sequential LTC scan: 1 block per batch ----------------
__global__ __launch_bounds__(1024) void scan_kernel(
    const float* __restrict__ wr, const float* __restrict__ tau,
    const float* __restrict__ av, const float* __restrict__ h0,
    float* __restrict__ ws, float* __restrict__ outh)
{
  const int b = blockIdx.x;
  const int tid = threadIdx.x;
  const int j = tid & 255, q = tid >> 8;
  __shared__ float h_s[256];
  __shared__ float part[4][256];
  float4 w4[16];
  const float4* wp = (const float4*)(wr + j*256 + q*64);
  #pragma unroll
  for (int i = 0; i < 16; ++i) w4[i] = wp[i];
  const float tinv = 1.f / tau[j];
  const float aj = av[j];
  if (tid < 256) h_s[tid] = h0[b*256 + tid];
  __syncthreads();
  const float* xw = ws + OFF_XW;
  float* hh = ws + OFF_HH;
  for (int t = 0; t < T_STEPS; ++t) {
    const float4* h4 = (const float4*)(h_s + q*64);
    float s0 = 0.f, s1 = 0.f, s2 = 0.f, s3 = 0.f;
    #pragma unroll
    for (int i = 0; i < 16; ++i) {
      float4 hv = h4[i];
      s0 = fmaf(w4[i].x, hv.x, s0); s1 = fmaf(w4[i].y, hv.y, s1);
      s2 = fmaf(w4[i].z, hv.z, s2); s3 = fmaf(w4[i].w, hv.w, s3);
    }
    part[q][j] = (s0 + s1) + (s2 + s3);
    __syncthreads();
    float pre = part[0][j] + part[1][j] + part[2][j] + part[3][j]
              + xw[(t*B_SZ + b)*HID + j];
    float f = 1.f - 2.f / (1.f + __expf(2.f * pre));
    float hv0 = h_s[j];
    float hn = fmaf(0.1f, fmaf(-(tinv + f), hv0, f * aj), hv0);
    __syncthreads();
    h_s[j] = hn;                       // 4 q-copies write identical value
    if (q == 0) hh[(t*B_SZ + b)*HID + j] = hn;
    __syncthreads();
  }
  if (q == 0) outh[b*HID + j] = h_s[j];
}

// ---------------- decoder MLP over all (t,b), parallel ----------------
__global__ __launch_bounds__(256) void dec_kernel(
    const float* __restrict__ db1, const float* __restrict__ db2,
    const float* __restrict__ db3, const float* __restrict__ ws,
    float* __restrict__ outc)
{
  const int bid = blockIdx.x;
  const int b = bid >> 8, t = bid & 255;
  const int tid = threadIdx.x;
  __shared__ float hloc[256];
  __shared__ float p1[2][128];
  __shared__ float y1s[128];
  __shared__ float p2[4][64];
  __shared__ float y2s[64];
  const float* hh  = ws + OFF_HH + (t*B_SZ + b)*HID;
  const float* d1T = ws + OFF_D1T;
  const float* d2T = ws + OFF_D2T;
  const float* d3T = ws + OFF_D3T;
  hloc[tid] = hh[tid];
  __syncthreads();
  {
    int i = tid & 127, hf = tid >> 7;
    float s = 0.f;
    for (int k = hf*128; k < hf*128 + 128; ++k) s = fmaf(hloc[k], d1T[k*128 + i], s);
    p1[hf][i] = s;
  }
  __syncthreads();
  if (tid < 128) y1s[tid] = fmaxf(p1[0][tid] + p1[1][tid] + db1[tid], 0.f);
  __syncthreads();
  {
    int i = tid & 63, r = tid >> 6;
    float s = 0.f;
    for (int k = r*32; k < r*32 + 32; ++k) s = fmaf(y1s[k], d2T[k*64 + i], s);
    p2[r][i] = s;
  }
  __syncthreads();
  if (tid < 64) y2s[tid] = fmaxf(p2[0][tid] + p2[1][tid] + p2[2][tid] + p2[3][tid] + db2[tid], 0.f);
  __syncthreads();
  if (tid < 6) {
    float s = db3[tid];
    for (int k = 0; k < 64; ++k) s = fmaf(y2s[k], d3T[k*6 + tid], s);
    outc[(b*T_STEPS + t)*6 + tid] = s;
  }
}

extern "C" void kernel_launch(void* const* d_in, const int* in_sizes, int n_in,
                              void* d_out, int out_size, void* d_ws, size_t ws_size,
                              hipStream_t stream)
{
  const float* frames = (const float*)d_in[0];
  const float* h0   = (const float*)d_in[1];
  const float* c1w  = (const float*)d_in[2];
  const float* c1b  = (const float*)d_in[3];
  const float* c2w  = (const float*)d_in[4];
  const float* c2b  = (const float*)d_in[5];
  const float* c3w  = (const float*)d_in[6];
  const float* c3b  = (const float*)d_in[7];
  const float* encw = (const float*)d_in[8];
  const float* encb = (const float*)d_in[9];
  const float* wr   = (const float*)d_in[10];
  const float* wi   = (const float*)d_in[11];
  const float* lb   = (const float*)d_in[12];
  const float* ltau = (const float*)d_in[13];
  const float* la   = (const float*)d_in[14];
  const float* dw1  = (const float*)d_in[15];
  const float* db1  = (const float*)d_in[16];
  const float* dw2  = (const float*)d_in[17];
  const float* db2  = (const float*)d_in[18];
  const float* dw3  = (const float*)d_in[19];
  const float* db3  = (const float*)d_in[20];
  float* out = (float*)d_out;
  float* ws  = (float*)d_ws;

  hipLaunchKernelGGL(prep_kernel, dim3(256), dim3(256), 0, stream,
                     c1w, c2w, c3w, encw, encb, wi, lb, dw1, dw2, dw3, ws);
  hipLaunchKernelGGL(enc_kernel, dim3(2048), dim3(256), 0, stream,
                     frames, c1b, c2b, c3b, ws);
  hipLaunchKernelGGL(scan_kernel, dim3(B_SZ), dim3(1024), 0, stream,
                     wr, ltau, la, h0, ws, out + 12288);
  hipLaunchKernelGGL(dec_kernel, dim3(2048), dim3(256), 0, stream,
                     db1, db2, db3, ws, out);
}

// Round 6
// 596.461 us; speedup vs baseline: 10.3214x; 2.2976x over previous
//
#include <hip/hip_runtime.h>

#define T_STEPS 256
#define B_SZ 8
#define HID 256

typedef _Float16 hv2 __attribute__((ext_vector_type(2)));
typedef _Float16 f16x4 __attribute__((ext_vector_type(4)));
typedef float f32x4 __attribute__((ext_vector_type(4)));
union H2U { hv2 h; unsigned u; };
union U2F { uint2 u; f16x4 h; };
__device__ inline hv2 u2h(unsigned u){ H2U c; c.u = u; return c.h; }
__device__ inline unsigned h2u(hv2 h){ H2U c; c.h = h; return c.u; }
__device__ inline hv2 relu2(hv2 v){
  unsigned u = h2u(v);
  unsigned s = (u & 0x80008000u) >> 15;
  u &= ~(s * 0xFFFFu);
  return u2h(u);
}
__device__ inline unsigned packh2f(float lo, float hi){
  hv2 h; h.x = (_Float16)lo; h.y = (_Float16)hi; return h2u(h);
}

// ---- workspace layout (dword offsets) ----
#define OFF_XW   0                 // (T,B,256) fused input projection  524288
#define OFF_HH   524288            // (T,B,256) hidden history          524288
#define OFF_WFT  1141760           // WfuseT[m][j] 128*256
#define OFF_BF   1174528           // bfuse[j] 256
#define OFF_D1T  1174784           // dec_w1T 256*128
#define OFF_D2T  1207552           // dec_w2T 128*64
#define OFF_D3T  1215744           // dec_w3T 64*6
#define OFF_W1P  1216128           // conv1 packed [k=27][pair=16] 432 dw
#define OFF_W2F  1216560           // conv2 B-frags [2][9][4][64][2] 9216 dw
#define OFF_W3F  1225776           // conv3 B-frags [36][8][64][2] 36864 dw

// ---------------- prep ----------------
__global__ __launch_bounds__(256) void prep_kernel(
    const float* __restrict__ conv1_w, const float* __restrict__ conv2_w,
    const float* __restrict__ conv3_w, const float* __restrict__ enc_w,
    const float* __restrict__ enc_b,  const float* __restrict__ ltc_wi,
    const float* __restrict__ ltc_b,  const float* __restrict__ dec_w1,
    const float* __restrict__ dec_w2, const float* __restrict__ dec_w3,
    float* __restrict__ ws)
{
  int gtid = blockIdx.x * 256 + threadIdx.x;
  int nth = gridDim.x * 256;
  unsigned* wsu = (unsigned*)ws;
  for (int e = gtid; e < 128 * 256; e += nth) {
    int j = e >> 7, m = e & 127;
    float s = 0.f;
    for (int k = 0; k < 256; ++k) s = fmaf(ltc_wi[j*256 + k], enc_w[k*128 + m], s);
    ws[OFF_WFT + m*256 + j] = s;
  }
  for (int e = gtid; e < 256; e += nth) {
    float s = ltc_b[e];
    for (int k = 0; k < 256; ++k) s = fmaf(ltc_wi[e*256 + k], enc_b[k], s);
    ws[OFF_BF + e] = s;
  }
  for (int e = gtid; e < 27*16; e += nth) { int k = e>>4, p = e&15;
    wsu[OFF_W1P+e] = packh2f(conv1_w[(2*p)*27 + k], conv1_w[(2*p+1)*27 + k]); }
  // conv2 B fragments: e = (((hp*9+kt)*4+nt)*64 + l)*2 + dpair
  for (int e = gtid; e < 9216; e += nth) {
    int dpair = e & 1;
    int tmp = e >> 1;
    int l = tmp & 63; tmp >>= 6;
    int nt = tmp & 3; tmp >>= 2;
    int kt = tmp % 9, hp = tmp / 9;
    int oc = nt*16 + (l & 15);
    int ic = hp*16 + ((l>>4)<<2) + (dpair<<1);
    int ky = kt/3, kx = kt%3;
    wsu[OFF_W2F + e] = packh2f(conv2_w[((oc*32 + ic)*3 + ky)*3 + kx],
                               conv2_w[((oc*32 + ic+1)*3 + ky)*3 + kx]);
  }
  // conv3 B fragments: e = ((kt*8+nt)*64 + l)*2 + dpair
  for (int e = gtid; e < 36864; e += nth) {
    int dpair = e & 1;
    int tmp = e >> 1;
    int l = tmp & 63; tmp >>= 6;
    int nt = tmp & 7; tmp >>= 3;
    int kt = tmp;
    int kyx = kt >> 2;
    int ky = kyx/3, kx = kyx%3;
    int ic = ((kt & 3) << 4) + ((l>>4)<<2) + (dpair<<1);
    int oc = nt*16 + (l & 15);
    wsu[OFF_W3F + e] = packh2f(conv3_w[((oc*64 + ic)*3 + ky)*3 + kx],
                               conv3_w[((oc*64 + ic+1)*3 + ky)*3 + kx]);
  }
  for (int e = gtid; e < 256*128;e += nth) { int k = e>>7, i = e&127; ws[OFF_D1T+e] = dec_w1[i*256 + k]; }
  for (int e = gtid; e < 128*64; e += nth) { int k = e>>6, i = e&63;  ws[OFF_D2T+e] = dec_w2[i*128 + k]; }
  for (int e = gtid; e < 64*6;   e += nth) { int k = e/6,  o = e%6;   ws[OFF_D3T+e] = dec_w3[o*64 + k]; }
}

// ---------------- fused per-frame CNN encoder: fp16 conv1 + MFMA conv2/conv3 ----------------
// LDS (dynamic 73408B): actA 8192dw | wst 9216dw | w1s 432dw | fmp 512 floats
__global__ __launch_bounds__(256, 2) void enc_kernel(
    const float* __restrict__ frames,
    const float* __restrict__ b1, const float* __restrict__ b2,
    const float* __restrict__ b3, float* __restrict__ ws)
{
  extern __shared__ __align__(16) unsigned lds[];
  unsigned* actA = lds;            // conv1 out (swizzled ch-last) / conv3-B dbuf
  unsigned* wst  = lds + 8192;     // conv2-B frags; later act2 (swizzled ch-last)
  unsigned* w1s  = lds + 17408;    // conv1 weights
  float* fmp = (float*)(lds + 17840);

  const int tid = threadIdx.x;
  const int l   = tid & 63;
  const int w   = tid >> 6;
  const int kg  = l >> 4;
  const int lc  = l & 15;
  const int bt  = blockIdx.x;
  const int b   = bt >> 8, t = bt & 255;
  const float* fr = frames + (size_t)bt * 12288;
  const unsigned* wsu = (const unsigned*)ws;

  // stage conv2-B (36KB) + conv1 weights
  {
    const uint4* src = (const uint4*)(wsu + OFF_W2F);
    uint4 tmp[9];
    #pragma unroll
    for (int q = 0; q < 9; ++q) tmp[q] = src[q*256 + tid];
    #pragma unroll
    for (int q = 0; q < 9; ++q) ((uint4*)wst)[q*256 + tid] = tmp[q];
    if (tid < 216) ((uint2*)w1s)[tid] = ((const uint2*)(wsu + OFF_W1P))[tid];
  }
  __syncthreads();

  f32x4 acc2[4][4];
  #pragma unroll
  for (int mi = 0; mi < 4; ++mi)
    #pragma unroll
    for (int nt = 0; nt < 4; ++nt) {
      float bb = b2[nt*16 + lc];
      acc2[mi][nt] = (f32x4){bb, bb, bb, bb};
    }

  for (int hp = 0; hp < 2; ++hp) {
    // ---- conv1 half (VALU fp16), swizzled channel-last write ----
    for (int p = 0; p < 4; ++p) {
      int pos = p*256 + tid;
      int y = pos >> 5, x = pos & 31;
      hv2 a1[8];
      #pragma unroll
      for (int o = 0; o < 8; ++o) { a1[o].x = (_Float16)b1[16*hp+2*o]; a1[o].y = (_Float16)b1[16*hp+2*o+1]; }
      for (int ic = 0; ic < 3; ++ic)
        for (int ky = 0; ky < 3; ++ky) {
          int iy = 2*y - 1 + ky;
          bool rok = (unsigned)iy < 64u;
          for (int kx = 0; kx < 3; ++kx) {
            int ix = 2*x - 1 + kx;
            float v = (rok && (unsigned)ix < 64u) ? fr[ic*4096 + iy*64 + ix] : 0.f;
            _Float16 hf = (_Float16)v;
            hv2 vs; vs.x = hf; vs.y = hf;
            int k = ic*9 + ky*3 + kx;
            uint4 wa = ((uint4*)w1s)[k*4 + hp*2];
            uint4 wb = ((uint4*)w1s)[k*4 + hp*2 + 1];
            a1[0] = vs * u2h(wa.x) + a1[0];
            a1[1] = vs * u2h(wa.y) + a1[1];
            a1[2] = vs * u2h(wa.z) + a1[2];
            a1[3] = vs * u2h(wa.w) + a1[3];
            a1[4] = vs * u2h(wb.x) + a1[4];
            a1[5] = vs * u2h(wb.y) + a1[5];
            a1[6] = vs * u2h(wb.z) + a1[6];
            a1[7] = vs * u2h(wb.w) + a1[7];
          }
        }
      unsigned r0 = h2u(relu2(a1[0])), r1 = h2u(relu2(a1[1]));
      unsigned r2 = h2u(relu2(a1[2])), r3 = h2u(relu2(a1[3]));
      unsigned r4 = h2u(relu2(a1[4])), r5 = h2u(relu2(a1[5]));
      unsigned r6 = h2u(relu2(a1[6])), r7 = h2u(relu2(a1[7]));
      int s = pos & 3;
      uint4 v0, v1;
      if (s & 1) { v0 = make_uint4(r2,r3,r0,r1); v1 = make_uint4(r6,r7,r4,r5); }
      else       { v0 = make_uint4(r0,r1,r2,r3); v1 = make_uint4(r4,r5,r6,r7); }
      int sl = (s >> 1) & 1;
      ((uint4*)actA)[pos*2 + sl]     = v0;
      ((uint4*)actA)[pos*2 + (1^sl)] = v1;
    }
    __syncthreads();
    // ---- conv2 half (MFMA): wave w owns M-tiles w*4..w*4+3, all 4 N-tiles ----
    #pragma unroll
    for (int ky = 0; ky < 3; ++ky)
      #pragma unroll
      for (int kx = 0; kx < 3; ++kx) {
        int kt = ky*3 + kx;
        U2F bf[4];
        #pragma unroll
        for (int nt = 0; nt < 4; ++nt)
          bf[nt].u = ((const uint2*)wst)[(((hp*9 + kt)*4 + nt)<<6) + l];
        #pragma unroll
        for (int mi = 0; mi < 4; ++mi) {
          int mt = w*4 + mi;
          int iy = 2*mt - 1 + ky;
          if (iy >= 0) {
            int ix = 2*lc - 1 + kx;
            bool okx = (unsigned)ix < 32u;
            int pos1 = iy*32 + (okx ? ix : 0);
            U2F av; av.u = ((const uint2*)actA)[pos1*4 + (kg ^ (pos1 & 3))];
            if (!okx) { av.u.x = 0u; av.u.y = 0u; }
            #pragma unroll
            for (int nt = 0; nt < 4; ++nt)
              acc2[mi][nt] = __builtin_amdgcn_mfma_f32_16x16x16f16(av.h, bf[nt].h, acc2[mi][nt], 0, 0, 0);
          }
        }
      }
    __syncthreads();
  }

  // ---- act2 (relu, swizzled ch-last fp16) into wst; stage conv3-B chunk0 into actA ----
  {
    const uint4* w3src = (const uint4*)(wsu + OFF_W3F);
    uint4 st[4];
    #pragma unroll
    for (int q = 0; q < 4; ++q) st[q] = w3src[q*256 + tid];
    _Float16* act2h = (_Float16*)wst;
    #pragma unroll
    for (int mi = 0; mi < 4; ++mi)
      #pragma unroll
      for (int nt = 0; nt < 4; ++nt)
        #pragma unroll
        for (int i = 0; i < 4; ++i) {
          int pos = (w*4 + mi)*16 + 4*kg + i;
          int oc = nt*16 + lc;
          float vv = fmaxf(acc2[mi][nt][i], 0.f);
          int ocp = (((oc >> 2) ^ (pos & 7)) << 2) + (oc & 3);
          act2h[pos*64 + ocp] = (_Float16)vv;
        }
    #pragma unroll
    for (int q = 0; q < 4; ++q) ((uint4*)actA)[q*256 + tid] = st[q];
  }

  f32x4 acc3[8];
  #pragma unroll
  for (int nt = 0; nt < 8; ++nt) { float bb = b3[nt*16 + lc]; acc3[nt] = (f32x4){bb, bb, bb, bb}; }
  const int y3 = (w*16 + lc) >> 3, x3 = lc & 7;
  const uint4* w3src = (const uint4*)(wsu + OFF_W3F);
  __syncthreads();

  // ---- conv3 (MFMA): 9 chunks (= kyx), 4 K-tiles each, dbuf B staging ----
  for (int c = 0; c < 9; ++c) {
    uint4 st[4];
    if (c < 8) {
      #pragma unroll
      for (int q = 0; q < 4; ++q) st[q] = w3src[(c+1)*1024 + q*256 + tid];
    }
    int ky = c / 3, kx = c % 3;
    int iy = 2*y3 - 1 + ky, ix = 2*x3 - 1 + kx;
    bool ok = ((unsigned)iy < 16u) && ((unsigned)ix < 16u);
    int posIn = (ok ? iy : 0)*16 + (ok ? ix : 0);
    int sw = posIn & 7;
    #pragma unroll
    for (int ktl = 0; ktl < 4; ++ktl) {
      int icb = ktl*4 + kg;
      U2F av; av.u = ((const uint2*)wst)[posIn*16 + (icb ^ sw)];
      if (!ok) { av.u.x = 0u; av.u.y = 0u; }
      #pragma unroll
      for (int nt = 0; nt < 8; ++nt) {
        U2F bv; bv.u = ((const uint2*)actA)[(c & 1)*2048 + ((ktl*8 + nt)<<6) + l];
        acc3[nt] = __builtin_amdgcn_mfma_f32_16x16x16f16(av.h, bv.h, acc3[nt], 0, 0, 0);
      }
    }
    if (c < 8) {
      #pragma unroll
      for (int q = 0; q < 4; ++q) ((uint4*)actA)[((c+1) & 1)*1024 + q*256 + tid] = st[q];
    }
    __syncthreads();
  }

  // ---- relu + spatial mean + fused encoder projection ----
  #pragma unroll
  for (int nt = 0; nt < 8; ++nt) {
    float s = 0.f;
    #pragma unroll
    for (int i = 0; i < 4; ++i) s += fmaxf(acc3[nt][i], 0.f);
    s += __shfl_xor(s, 16);
    s += __shfl_xor(s, 32);
    if (l < 16) fmp[w*128 + nt*16 + l] = s;
  }
  __syncthreads();
  if (tid < 128) {
    float s = fmp[tid] + fmp[128 + tid] + fmp[256 + tid] + fmp[384 + tid];
    fmp[tid] = s * (1.f/64.f);
  }
  __syncthreads();
  {
    float accx = ws[OFF_BF + tid];
    const float* wfT = ws + OFF_WFT;
    for (int m = 0; m < 128; ++m) accx = fmaf(fmp[m], wfT[m*256 + tid], accx);
    ws[OFF_XW + (t*B_SZ + b)*HID + tid] = accx;
  }
}

// ---------------- sequential LTC scan: 1 block per batch ----------------
__global__ __launch_bounds__(1024) void scan_kernel(
    const float* __restrict__ wr, const float* __restrict__ tau,
    const float* __restrict__ av, const float* __restrict__ h0,
    float* __restrict__ ws, float* __restrict__ outh)
{
  const int b = blockIdx.x;
  const int tid = threadIdx.x;
  const int j = tid & 255, q = tid >> 8;
  __shared__ float h_s[256];
  __shared__ float part[4][256];
  float4 w4[16];
  const float4* wp = (const float4*)(wr + j*256 + q*64);
  #pragma unroll
  for (int i = 0; i < 16; ++i) w4[i] = wp[i];
  const float tinv = 1.f / tau[j];
  const float aj = av[j];
  if (tid < 256) h_s[tid] = h0[b*256 + tid];
  __syncthreads();
  const float* xw = ws + OFF_XW;
  float* hh = ws + OFF_HH;
  for (int t = 0; t < T_STEPS; ++t) {
    const float4* h4 = (const float4*)(h_s + q*64);
    float s0 = 0.f, s1 = 0.f, s2 = 0.f, s3 = 0.f;
    #pragma unroll
    for (int i = 0; i < 16; ++i) {
      float4 hv = h4[i];
      s0 = fmaf(w4[i].x, hv.x, s0); s1 = fmaf(w4[i].y, hv.y, s1);
      s2 = fmaf(w4[i].z, hv.z, s2); s3 = fmaf(w4[i].w, hv.w, s3);
    }
    part[q][j] = (s0 + s1) + (s2 + s3);
    __syncthreads();
    float pre = part[0][j] + part[1][j] + part[2][j] + part[3][j]
              + xw[(t*B_SZ + b)*HID + j];
    float f = 1.f - 2.f / (1.f + __expf(2.f * pre));
    float hv0 = h_s[j];
    float hn = fmaf(0.1f, fmaf(-(tinv + f), hv0, f * aj), hv0);
    __syncthreads();
    h_s[j] = hn;
    if (q == 0) hh[(t*B_SZ + b)*HID + j] = hn;
    __syncthreads();
  }
  if (q == 0) outh[b*HID + j] = h_s[j];
}

// ---------------- decoder MLP over all (t,b), parallel ----------------
__global__ __launch_bounds__(256) void dec_kernel(
    const float* __restrict__ db1, const float* __restrict__ db2,
    const float* __restrict__ db3, const float* __restrict__ ws,
    float* __restrict__ outc)
{
  const int bid = blockIdx.x;
  const int b = bid >> 8, t = bid & 255;
  const int tid = threadIdx.x;
  __shared__ float hloc[256];
  __shared__ float p1[2][128];
  __shared__ float y1s[128];
  __shared__ float p2[4][64];
  __shared__ float y2s[64];
  const float* hh  = ws + OFF_HH + (t*B_SZ + b)*HID;
  const float* d1T = ws + OFF_D1T;
  const float* d2T = ws + OFF_D2T;
  const float* d3T = ws + OFF_D3T;
  hloc[tid] = hh[tid];
  __syncthreads();
  {
    int i = tid & 127, hf = tid >> 7;
    float s = 0.f;
    for (int k = hf*128; k < hf*128 + 128; ++k) s = fmaf(hloc[k], d1T[k*128 + i], s);
    p1[hf][i] = s;
  }
  __syncthreads();
  if (tid < 128) y1s[tid] = fmaxf(p1[0][tid] + p1[1][tid] + db1[tid], 0.f);
  __syncthreads();
  {
    int i = tid & 63, r = tid >> 6;
    float s = 0.f;
    for (int k = r*32; k < r*32 + 32; ++k) s = fmaf(y1s[k], d2T[k*64 + i], s);
    p2[r][i] = s;
  }
  __syncthreads();
  if (tid < 64) y2s[tid] = fmaxf(p2[0][tid] + p2[1][tid] + p2[2][tid] + p2[3][tid] + db2[tid], 0.f);
  __syncthreads();
  if (tid < 6) {
    float s = db3[tid];
    for (int k = 0; k < 64; ++k) s = fmaf(y2s[k], d3T[k*6 + tid], s);
    outc[(b*T_STEPS + t)*6 + tid] = s;
  }
}

extern "C" void kernel_launch(void* const* d_in, const int* in_sizes, int n_in,
                              void* d_out, int out_size, void* d_ws, size_t ws_size,
                              hipStream_t stream)
{
  const float* frames = (const float*)d_in[0];
  const float* h0   = (const float*)d_in[1];
  const float* c1w  = (const float*)d_in[2];
  const float* c1b  = (const float*)d_in[3];
  const float* c2w  = (const float*)d_in[4];
  const float* c2b  = (const float*)d_in[5];
  const float* c3w  = (const float*)d_in[6];
  const float* c3b  = (const float*)d_in[7];
  const float* encw = (const float*)d_in[8];
  const float* encb = (const float*)d_in[9];
  const float* wr   = (const float*)d_in[10];
  const float* wi   = (const float*)d_in[11];
  const float* lb   = (const float*)d_in[12];
  const float* ltau = (const float*)d_in[13];
  const float* la   = (const float*)d_in[14];
  const float* dw1  = (const float*)d_in[15];
  const float* db1  = (const float*)d_in[16];
  const float* dw2  = (const float*)d_in[17];
  const float* db2  = (const float*)d_in[18];
  const float* dw3  = (const float*)d_in[19];
  const float* db3  = (const float*)d_in[20];
  float* out = (float*)d_out;
  float* ws  = (float*)d_ws;

  hipLaunchKernelGGL(prep_kernel, dim3(256), dim3(256), 0, stream,
                     c1w, c2w, c3w, encw, encb, wi, lb, dw1, dw2, dw3, ws);
  hipLaunchKernelGGL(enc_kernel, dim3(2048), dim3(256), 73408, stream,
                     frames, c1b, c2b, c3b, ws);
  hipLaunchKernelGGL(scan_kernel, dim3(B_SZ), dim3(1024), 0, stream,
                     wr, ltau, la, h0, ws, out + 12288);
  hipLaunchKernelGGL(dec_kernel, dim3(2048), dim3(256), 0, stream,
                     db1, db2, db3, ws, out);
}

// Round 7
// 487.990 us; speedup vs baseline: 12.6157x; 1.2223x over previous
//
#include <hip/hip_runtime.h>

#define T_STEPS 256
#define B_SZ 8
#define HID 256

typedef _Float16 hv2 __attribute__((ext_vector_type(2)));
typedef _Float16 f16x4 __attribute__((ext_vector_type(4)));
typedef float f32x4 __attribute__((ext_vector_type(4)));
union H2U { hv2 h; unsigned u; };
union U2F { uint2 u; f16x4 h; };
__device__ inline hv2 u2h(unsigned u){ H2U c; c.u = u; return c.h; }
__device__ inline unsigned h2u(hv2 h){ H2U c; c.h = h; return c.u; }
__device__ inline hv2 relu2(hv2 v){
  unsigned u = h2u(v);
  unsigned s = (u & 0x80008000u) >> 15;
  u &= ~(s * 0xFFFFu);
  return u2h(u);
}
__device__ inline unsigned packh2f(float lo, float hi){
  hv2 h; h.x = (_Float16)lo; h.y = (_Float16)hi; return h2u(h);
}

// ---- workspace layout (dword offsets) ----
#define OFF_XW   0                 // (T,B,256) fused input projection  524288
#define OFF_HH   524288            // (T,B,256) hidden history          524288
#define OFF_WFT  1141760           // WfuseT[m][j] 128*256
#define OFF_BF   1174528           // bfuse[j] 256
#define OFF_D1T  1174784           // dec_w1T 256*128
#define OFF_D2T  1207552           // dec_w2T 128*64
#define OFF_D3T  1215744           // dec_w3T 64*6
#define OFF_W1P  1216128           // conv1 packed [k=27][pair=16] 432 dw
#define OFF_W2F  1216560           // conv2 B-frags [2][9][4][64][2] 9216 dw
#define OFF_W3F  1225776           // conv3 B-frags [36][8][64][2] 36864 dw
#define OFF_WRP  1262640           // ltc_wr fp16 pairs [q=4][j=256][i=32] 32768 dw

// ---------------- prep ----------------
__global__ __launch_bounds__(256) void prep_kernel(
    const float* __restrict__ conv1_w, const float* __restrict__ conv2_w,
    const float* __restrict__ conv3_w, const float* __restrict__ enc_w,
    const float* __restrict__ enc_b,  const float* __restrict__ ltc_wi,
    const float* __restrict__ ltc_b,  const float* __restrict__ ltc_wr,
    const float* __restrict__ dec_w1,
    const float* __restrict__ dec_w2, const float* __restrict__ dec_w3,
    float* __restrict__ ws)
{
  int gtid = blockIdx.x * 256 + threadIdx.x;
  int nth = gridDim.x * 256;
  unsigned* wsu = (unsigned*)ws;
  for (int e = gtid; e < 128 * 256; e += nth) {
    int j = e >> 7, m = e & 127;
    float s = 0.f;
    for (int k = 0; k < 256; ++k) s = fmaf(ltc_wi[j*256 + k], enc_w[k*128 + m], s);
    ws[OFF_WFT + m*256 + j] = s;
  }
  for (int e = gtid; e < 256; e += nth) {
    float s = ltc_b[e];
    for (int k = 0; k < 256; ++k) s = fmaf(ltc_wi[e*256 + k], enc_b[k], s);
    ws[OFF_BF + e] = s;
  }
  for (int e = gtid; e < 27*16; e += nth) { int k = e>>4, p = e&15;
    wsu[OFF_W1P+e] = packh2f(conv1_w[(2*p)*27 + k], conv1_w[(2*p+1)*27 + k]); }
  // conv2 B fragments: e = (((hp*9+kt)*4+nt)*64 + l)*2 + dpair
  for (int e = gtid; e < 9216; e += nth) {
    int dpair = e & 1;
    int tmp = e >> 1;
    int l = tmp & 63; tmp >>= 6;
    int nt = tmp & 3; tmp >>= 2;
    int kt = tmp % 9, hp = tmp / 9;
    int oc = nt*16 + (l & 15);
    int ic = hp*16 + ((l>>4)<<2) + (dpair<<1);
    int ky = kt/3, kx = kt%3;
    wsu[OFF_W2F + e] = packh2f(conv2_w[((oc*32 + ic)*3 + ky)*3 + kx],
                               conv2_w[((oc*32 + ic+1)*3 + ky)*3 + kx]);
  }
  // conv3 B fragments: e = ((kt*8+nt)*64 + l)*2 + dpair
  for (int e = gtid; e < 36864; e += nth) {
    int dpair = e & 1;
    int tmp = e >> 1;
    int l = tmp & 63; tmp >>= 6;
    int nt = tmp & 7; tmp >>= 3;
    int kt = tmp;
    int kyx = kt >> 2;
    int ky = kyx/3, kx = kyx%3;
    int ic = ((kt & 3) << 4) + ((l>>4)<<2) + (dpair<<1);
    int oc = nt*16 + (l & 15);
    wsu[OFF_W3F + e] = packh2f(conv3_w[((oc*64 + ic)*3 + ky)*3 + kx],
                               conv3_w[((oc*64 + ic+1)*3 + ky)*3 + kx]);
  }
  // ltc_wr fp16 pairs: idx = (q*256 + j)*32 + i  -> (wr[j, q*64+2i], wr[j, q*64+2i+1])
  for (int e = gtid; e < 32768; e += nth) {
    int i = e & 31;
    int j = (e >> 5) & 255;
    int q = e >> 13;
    wsu[OFF_WRP + e] = packh2f(ltc_wr[j*256 + q*64 + 2*i],
                               ltc_wr[j*256 + q*64 + 2*i + 1]);
  }
  for (int e = gtid; e < 256*128;e += nth) { int k = e>>7, i = e&127; ws[OFF_D1T+e] = dec_w1[i*256 + k]; }
  for (int e = gtid; e < 128*64; e += nth) { int k = e>>6, i = e&63;  ws[OFF_D2T+e] = dec_w2[i*128 + k]; }
  for (int e = gtid; e < 64*6;   e += nth) { int k = e/6,  o = e%6;   ws[OFF_D3T+e] = dec_w3[o*64 + k]; }
}

// ---------------- fused per-frame CNN encoder: fp16 conv1 + MFMA conv2/conv3 ----------------
// LDS (dynamic 73408B): actA 8192dw | wst 9216dw | w1s 432dw | fmp 512 floats
__global__ __launch_bounds__(256, 2) void enc_kernel(
    const float* __restrict__ frames,
    const float* __restrict__ b1, const float* __restrict__ b2,
    const float* __restrict__ b3, float* __restrict__ ws)
{
  extern __shared__ __align__(16) unsigned lds[];
  unsigned* actA = lds;            // conv1 out (swizzled ch-last) / conv3-B dbuf
  unsigned* wst  = lds + 8192;     // conv2-B frags; later act2 (swizzled ch-last)
  unsigned* w1s  = lds + 17408;    // conv1 weights
  float* fmp = (float*)(lds + 17840);

  const int tid = threadIdx.x;
  const int l   = tid & 63;
  const int w   = tid >> 6;
  const int kg  = l >> 4;
  const int lc  = l & 15;
  const int bt  = blockIdx.x;
  const int b   = bt >> 8, t = bt & 255;
  const float* fr = frames + (size_t)bt * 12288;
  const unsigned* wsu = (const unsigned*)ws;

  // stage conv2-B (36KB) + conv1 weights
  {
    const uint4* src = (const uint4*)(wsu + OFF_W2F);
    uint4 tmp[9];
    #pragma unroll
    for (int q = 0; q < 9; ++q) tmp[q] = src[q*256 + tid];
    #pragma unroll
    for (int q = 0; q < 9; ++q) ((uint4*)wst)[q*256 + tid] = tmp[q];
    if (tid < 216) ((uint2*)w1s)[tid] = ((const uint2*)(wsu + OFF_W1P))[tid];
  }
  __syncthreads();

  f32x4 acc2[4][4];
  #pragma unroll
  for (int mi = 0; mi < 4; ++mi)
    #pragma unroll
    for (int nt = 0; nt < 4; ++nt) {
      float bb = b2[nt*16 + lc];
      acc2[mi][nt] = (f32x4){bb, bb, bb, bb};
    }

  for (int hp = 0; hp < 2; ++hp) {
    // ---- conv1 half (VALU fp16), swizzled channel-last write ----
    for (int p = 0; p < 4; ++p) {
      int pos = p*256 + tid;
      int y = pos >> 5, x = pos & 31;
      hv2 a1[8];
      #pragma unroll
      for (int o = 0; o < 8; ++o) { a1[o].x = (_Float16)b1[16*hp+2*o]; a1[o].y = (_Float16)b1[16*hp+2*o+1]; }
      for (int ic = 0; ic < 3; ++ic)
        for (int ky = 0; ky < 3; ++ky) {
          int iy = 2*y - 1 + ky;
          bool rok = (unsigned)iy < 64u;
          for (int kx = 0; kx < 3; ++kx) {
            int ix = 2*x - 1 + kx;
            float v = (rok && (unsigned)ix < 64u) ? fr[ic*4096 + iy*64 + ix] : 0.f;
            _Float16 hf = (_Float16)v;
            hv2 vs; vs.x = hf; vs.y = hf;
            int k = ic*9 + ky*3 + kx;
            uint4 wa = ((uint4*)w1s)[k*4 + hp*2];
            uint4 wb = ((uint4*)w1s)[k*4 + hp*2 + 1];
            a1[0] = vs * u2h(wa.x) + a1[0];
            a1[1] = vs * u2h(wa.y) + a1[1];
            a1[2] = vs * u2h(wa.z) + a1[2];
            a1[3] = vs * u2h(wa.w) + a1[3];
            a1[4] = vs * u2h(wb.x) + a1[4];
            a1[5] = vs * u2h(wb.y) + a1[5];
            a1[6] = vs * u2h(wb.z) + a1[6];
            a1[7] = vs * u2h(wb.w) + a1[7];
          }
        }
      unsigned r0 = h2u(relu2(a1[0])), r1 = h2u(relu2(a1[1]));
      unsigned r2 = h2u(relu2(a1[2])), r3 = h2u(relu2(a1[3]));
      unsigned r4 = h2u(relu2(a1[4])), r5 = h2u(relu2(a1[5]));
      unsigned r6 = h2u(relu2(a1[6])), r7 = h2u(relu2(a1[7]));
      int s = pos & 3;
      uint4 v0, v1;
      if (s & 1) { v0 = make_uint4(r2,r3,r0,r1); v1 = make_uint4(r6,r7,r4,r5); }
      else       { v0 = make_uint4(r0,r1,r2,r3); v1 = make_uint4(r4,r5,r6,r7); }
      int sl = (s >> 1) & 1;
      ((uint4*)actA)[pos*2 + sl]     = v0;
      ((uint4*)actA)[pos*2 + (1^sl)] = v1;
    }
    __syncthreads();
    // ---- conv2 half (MFMA): wave w owns M-tiles w*4..w*4+3, all 4 N-tiles ----
    #pragma unroll
    for (int ky = 0; ky < 3; ++ky)
      #pragma unroll
      for (int kx = 0; kx < 3; ++kx) {
        int kt = ky*3 + kx;
        U2F bf[4];
        #pragma unroll
        for (int nt = 0; nt < 4; ++nt)
          bf[nt].u = ((const uint2*)wst)[(((hp*9 + kt)*4 + nt)<<6) + l];
        #pragma unroll
        for (int mi = 0; mi < 4; ++mi) {
          int mt = w*4 + mi;
          int iy = 2*mt - 1 + ky;
          if (iy >= 0) {
            int ix = 2*lc - 1 + kx;
            bool okx = (unsigned)ix < 32u;
            int pos1 = iy*32 + (okx ? ix : 0);
            U2F av; av.u = ((const uint2*)actA)[pos1*4 + (kg ^ (pos1 & 3))];
            if (!okx) { av.u.x = 0u; av.u.y = 0u; }
            #pragma unroll
            for (int nt = 0; nt < 4; ++nt)
              acc2[mi][nt] = __builtin_amdgcn_mfma_f32_16x16x16f16(av.h, bf[nt].h, acc2[mi][nt], 0, 0, 0);
          }
        }
      }
    __syncthreads();
  }

  // ---- act2 (relu, swizzled ch-last fp16) into wst; stage conv3-B chunk0 into actA ----
  {
    const uint4* w3src = (const uint4*)(wsu + OFF_W3F);
    uint4 st[4];
    #pragma unroll
    for (int q = 0; q < 4; ++q) st[q] = w3src[q*256 + tid];
    _Float16* act2h = (_Float16*)wst;
    #pragma unroll
    for (int mi = 0; mi < 4; ++mi)
      #pragma unroll
      for (int nt = 0; nt < 4; ++nt)
        #pragma unroll
        for (int i = 0; i < 4; ++i) {
          int pos = (w*4 + mi)*16 + 4*kg + i;
          int oc = nt*16 + lc;
          float vv = fmaxf(acc2[mi][nt][i], 0.f);
          int ocp = (((oc >> 2) ^ (pos & 7)) << 2) + (oc & 3);
          act2h[pos*64 + ocp] = (_Float16)vv;
        }
    #pragma unroll
    for (int q = 0; q < 4; ++q) ((uint4*)actA)[q*256 + tid] = st[q];
  }

  f32x4 acc3[8];
  #pragma unroll
  for (int nt = 0; nt < 8; ++nt) { float bb = b3[nt*16 + lc]; acc3[nt] = (f32x4){bb, bb, bb, bb}; }
  const int y3 = (w*16 + lc) >> 3, x3 = lc & 7;
  const uint4* w3src = (const uint4*)(wsu + OFF_W3F);
  __syncthreads();

  // ---- conv3 (MFMA): 9 chunks (= kyx), 4 K-tiles each, dbuf B staging ----
  for (int c = 0; c < 9; ++c) {
    uint4 st[4];
    if (c < 8) {
      #pragma unroll
      for (int q = 0; q < 4; ++q) st[q] = w3src[(c+1)*1024 + q*256 + tid];
    }
    int ky = c / 3, kx = c % 3;
    int iy = 2*y3 - 1 + ky, ix = 2*x3 - 1 + kx;
    bool ok = ((unsigned)iy < 16u) && ((unsigned)ix < 16u);
    int posIn = (ok ? iy : 0)*16 + (ok ? ix : 0);
    int sw = posIn & 7;
    #pragma unroll
    for (int ktl = 0; ktl < 4; ++ktl) {
      int icb = ktl*4 + kg;
      U2F av; av.u = ((const uint2*)wst)[posIn*16 + (icb ^ sw)];
      if (!ok) { av.u.x = 0u; av.u.y = 0u; }
      #pragma unroll
      for (int nt = 0; nt < 8; ++nt) {
        U2F bv; bv.u = ((const uint2*)actA)[(c & 1)*2048 + ((ktl*8 + nt)<<6) + l];
        acc3[nt] = __builtin_amdgcn_mfma_f32_16x16x16f16(av.h, bv.h, acc3[nt], 0, 0, 0);
      }
    }
    if (c < 8) {
      #pragma unroll
      for (int q = 0; q < 4; ++q) ((uint4*)actA)[((c+1) & 1)*1024 + q*256 + tid] = st[q];
    }
    __syncthreads();
  }

  // ---- relu + spatial mean + fused encoder projection ----
  #pragma unroll
  for (int nt = 0; nt < 8; ++nt) {
    float s = 0.f;
    #pragma unroll
    for (int i = 0; i < 4; ++i) s += fmaxf(acc3[nt][i], 0.f);
    s += __shfl_xor(s, 16);
    s += __shfl_xor(s, 32);
    if (l < 16) fmp[w*128 + nt*16 + l] = s;
  }
  __syncthreads();
  if (tid < 128) {
    float s = fmp[tid] + fmp[128 + tid] + fmp[256 + tid] + fmp[384 + tid];
    fmp[tid] = s * (1.f/64.f);
  }
  __syncthreads();
  {
    float accx = ws[OFF_BF + tid];
    const float* wfT = ws + OFF_WFT;
    for (int m = 0; m < 128; ++m) accx = fmaf(fmp[m], wfT[m*256 + tid], accx);
    ws[OFF_XW + (t*B_SZ + b)*HID + tid] = accx;
  }
}

// ---------------- sequential LTC scan: 1 block per batch, fp16 reg-resident weights ----------------
__global__ __launch_bounds__(1024) void scan_kernel(
    const float* __restrict__ tau, const float* __restrict__ av,
    const float* __restrict__ h0,
    float* __restrict__ ws, float* __restrict__ outh)
{
  const int b = blockIdx.x;
  const int tid = threadIdx.x;
  const int j = tid & 255, q = tid >> 8;     // q = 0..3: h-range [q*64, q*64+64)
  __shared__ float hf[256];
  __shared__ unsigned hp16[128];             // fp16 h pairs
  __shared__ float part[4][256];
  __shared__ float hbuf[16*256];             // 16-step hh staging (16KB)

  // fp16 weight pairs, register-resident: 8 uint4 = 32 VGPR
  uint4 wv[8];
  {
    const uint4* wp = (const uint4*)((const unsigned*)ws + OFF_WRP + (q*256 + j)*32);
    #pragma unroll
    for (int r = 0; r < 8; ++r) wv[r] = wp[r];
  }
  const float tinv = 1.f / tau[j];
  const float aj = av[j];
  const float* xw = ws + OFF_XW;
  float* hh = ws + OFF_HH;

  // init h (fp32 + packed fp16)
  {
    float hv0 = h0[b*256 + j];
    float hvn = __shfl_xor(hv0, 1);
    if (q == 0) {
      hf[j] = hv0;
      if (!(j & 1)) hp16[j >> 1] = packh2f(hv0, hvn);
    }
  }
  float xw_pref = xw[(0*B_SZ + b)*HID + j];
  __syncthreads();

  for (int t = 0; t < T_STEPS; ++t) {
    float xwv = xw_pref;
    xw_pref = xw[((t+1)*B_SZ + b)*HID + j];   // t=255 reads into HH region: harmless, unused
    // matvec partial over 64 h-elems (fp16 packed)
    hv2 acc = {(_Float16)0.f, (_Float16)0.f};
    const uint4* hq = (const uint4*)hp16 + q*8;
    #pragma unroll
    for (int r = 0; r < 8; ++r) {
      uint4 hvp = hq[r];
      acc = u2h(hvp.x) * u2h(wv[r].x) + acc;
      acc = u2h(hvp.y) * u2h(wv[r].y) + acc;
      acc = u2h(hvp.z) * u2h(wv[r].z) + acc;
      acc = u2h(hvp.w) * u2h(wv[r].w) + acc;
    }
    float hv0 = hf[j];
    part[q][j] = (float)acc.x + (float)acc.y;
    __syncthreads();
    float pre = part[0][j] + part[1][j] + part[2][j] + part[3][j] + xwv;
    float f = 1.f - 2.f / (1.f + __expf(2.f * pre));
    float hn = fmaf(0.1f, fmaf(-(tinv + f), hv0, f * aj), hv0);
    float hnn = __shfl_xor(hn, 1);
    if (q == 0) {
      hf[j] = hn;
      hbuf[(t & 15)*256 + j] = hn;
      if (!(j & 1)) hp16[j >> 1] = packh2f(hn, hnn);
    }
    __syncthreads();
    if ((t & 15) == 15) {   // flush 16 steps of hh (reads safe: next hbuf write is after next barrier)
      int base = t - 15;
      int st = tid >> 6;
      int col = (tid & 63) << 2;
      *(float4*)(hh + ((base + st)*B_SZ + b)*HID + col) = *(float4*)(hbuf + st*256 + col);
    }
  }
  if (q == 0) outh[b*HID + j] = hf[j];
}

// ---------------- decoder MLP over all (t,b), parallel ----------------
__global__ __launch_bounds__(256) void dec_kernel(
    const float* __restrict__ db1, const float* __restrict__ db2,
    const float* __restrict__ db3, const float* __restrict__ ws,
    float* __restrict__ outc)
{
  const int bid = blockIdx.x;
  const int b = bid >> 8, t = bid & 255;
  const int tid = threadIdx.x;
  __shared__ float hloc[256];
  __shared__ float p1[2][128];
  __shared__ float y1s[128];
  __shared__ float p2[4][64];
  __shared__ float y2s[64];
  const float* hh  = ws + OFF_HH + (t*B_SZ + b)*HID;
  const float* d1T = ws + OFF_D1T;
  const float* d2T = ws + OFF_D2T;
  const float* d3T = ws + OFF_D3T;
  hloc[tid] = hh[tid];
  __syncthreads();
  {
    int i = tid & 127, hf = tid >> 7;
    float s = 0.f;
    for (int k = hf*128; k < hf*128 + 128; ++k) s = fmaf(hloc[k], d1T[k*128 + i], s);
    p1[hf][i] = s;
  }
  __syncthreads();
  if (tid < 128) y1s[tid] = fmaxf(p1[0][tid] + p1[1][tid] + db1[tid], 0.f);
  __syncthreads();
  {
    int i = tid & 63, r = tid >> 6;
    float s = 0.f;
    for (int k = r*32; k < r*32 + 32; ++k) s = fmaf(y1s[k], d2T[k*64 + i], s);
    p2[r][i] = s;
  }
  __syncthreads();
  if (tid < 64) y2s[tid] = fmaxf(p2[0][tid] + p2[1][tid] + p2[2][tid] + p2[3][tid] + db2[tid], 0.f);
  __syncthreads();
  if (tid < 6) {
    float s = db3[tid];
    for (int k = 0; k < 64; ++k) s = fmaf(y2s[k], d3T[k*6 + tid], s);
    outc[(b*T_STEPS + t)*6 + tid] = s;
  }
}

extern "C" void kernel_launch(void* const* d_in, const int* in_sizes, int n_in,
                              void* d_out, int out_size, void* d_ws, size_t ws_size,
                              hipStream_t stream)
{
  const float* frames = (const float*)d_in[0];
  const float* h0   = (const float*)d_in[1];
  const float* c1w  = (const float*)d_in[2];
  const float* c1b  = (const float*)d_in[3];
  const float* c2w  = (const float*)d_in[4];
  const float* c2b  = (const float*)d_in[5];
  const float* c3w  = (const float*)d_in[6];
  const float* c3b  = (const float*)d_in[7];
  const float* encw = (const float*)d_in[8];
  const float* encb = (const float*)d_in[9];
  const float* wr   = (const float*)d_in[10];
  const float* wi   = (const float*)d_in[11];
  const float* lb   = (const float*)d_in[12];
  const float* ltau = (const float*)d_in[13];
  const float* la   = (const float*)d_in[14];
  const float* dw1  = (const float*)d_in[15];
  const float* db1  = (const float*)d_in[16];
  const float* dw2  = (const float*)d_in[17];
  const float* db2  = (const float*)d_in[18];
  const float* dw3  = (const float*)d_in[19];
  const float* db3  = (const float*)d_in[20];
  float* out = (float*)d_out;
  float* ws  = (float*)d_ws;

  hipLaunchKernelGGL(prep_kernel, dim3(256), dim3(256), 0, stream,
                     c1w, c2w, c3w, encw, encb, wi, lb, wr, dw1, dw2, dw3, ws);
  hipLaunchKernelGGL(enc_kernel, dim3(2048), dim3(256), 73408, stream,
                     frames, c1b, c2b, c3b, ws);
  hipLaunchKernelGGL(scan_kernel, dim3(B_SZ), dim3(1024), 0, stream,
                     ltau, la, h0, ws, out + 12288);
  hipLaunchKernelGGL(dec_kernel, dim3(2048), dim3(256), 0, stream,
                     db1, db2, db3, ws, out);
}